// Round 12
// baseline (261.679 us; speedup 1.0000x reference)
//
#include <hip/hip_runtime.h>

// Problem constants
constexpr int Bb = 1024;   // batch
constexpr int Ii = 256;    // in features
constexpr int Oo = 256;    // out features
constexpr int Kk = 128;    // knots
constexpr int NCH = 8;     // i-chunks (XCD-aligned)

typedef unsigned short u16;
typedef unsigned int u32;
typedef u16 ushort4v __attribute__((ext_vector_type(4)));

__device__ __forceinline__ float bf16u_to_f(u16 u) {
    union { u32 ui; float f; } c;
    c.ui = ((u32)u) << 16;
    return c.f;
}
__device__ __forceinline__ u16 f_to_bf16(float f) {  // round-to-nearest-even
    union { float f; u32 u; } c; c.f = f;
    u32 r = c.u + 0x7fffu + ((c.u >> 16) & 1u);
    return (u16)(r >> 16);
}

// Kernel A: permute+scale Cs[o][i][k] -> Cp[i][k][o] bf16 via LDS transpose.
// 1024 blocks, XCD-ALIGNED numbering: chunk = blk & 7 (same mapping as
// kmain's readers) -> chunk c's 2 MB Cp slice is written by XCD c and stays
// valid-clean in XCD c's L2 for kmain's local-L2 gather hits.
// Tile = 128 o x 64 k; reads coalesced along k, writes coalesced along o;
// LDS pitch 66 u16 -> conflict-free. Tails: blocks<256 build Wt[i][o]=W[o][i];
// block 256 zeroes the 128 b-tile arrival counters used by kmain's fused
// reduction (stream order makes them visible to kmain).
__global__ __launch_bounds__(256) void kperm(const float* __restrict__ cs,
                                             const float* __restrict__ scale,
                                             const float* __restrict__ wbase,
                                             u16* __restrict__ cp,
                                             float* __restrict__ wt,
                                             u32* __restrict__ cnt) {
    __shared__ u16 T[128 * 66];       // [o_local][k_local], pitch 66
    int blk = blockIdx.x;
    int chunk = blk & 7;
    int sub = blk >> 3;               // 0..127
    int i  = chunk * 32 + (sub & 31); // i within this XCD's chunk
    int oh = (sub >> 5) & 1, kh = (sub >> 6) & 1;
    int o0 = oh << 7, kb = kh << 6;
    int t = threadIdx.x;

    // Phase 1: load Cs rows (float4 along k), scale, bf16 -> LDS
    {
        int c4 = t & 15;              // float4 index within the 64-k half
        int rb = t >> 4;              // 0..15
        const float4* cs4 = (const float4*)cs;
#pragma unroll
        for (int p = 0; p < 8; ++p) {
            int r = p * 16 + rb;      // o_local 0..127
            int o = o0 + r;
            float sc = scale[o * Ii + i];
            float4 val = cs4[(size_t)(o * Ii + i) * (Kk / 4) + kh * 16 + c4];
            int kl = c4 * 4;
            T[r * 66 + kl + 0] = f_to_bf16(val.x * sc);
            T[r * 66 + kl + 1] = f_to_bf16(val.y * sc);
            T[r * 66 + kl + 2] = f_to_bf16(val.z * sc);
            T[r * 66 + kl + 3] = f_to_bf16(val.w * sc);
        }
    }
    __syncthreads();
    // Phase 2: write Cp[i][kb+kl][o0..o0+128], lanes <-> o (u32 = 2 o)
    {
        int og = t & 63;              // o-pair index (o = og*2, og*2+1)
        int kg = t >> 6;              // 0..3, 16 k-rows each
#pragma unroll
        for (int m = 0; m < 16; ++m) {
            int kl = kg * 16 + m;
            u32 lo = T[(og * 2) * 66 + kl];
            u32 hi = T[(og * 2 + 1) * 66 + kl];
            *(u32*)&cp[((size_t)i * Kk + kb + kl) * Oo + o0 + og * 2] = lo | (hi << 16);
        }
    }
    // Tails
    if (blk < 256) {                  // Wt[i][o] = W[o][i]
        int gid = blk * 256 + t;
        wt[gid] = wbase[(gid & 255) * Ii + (gid >> 8)];
    }
    if (blk == 256 && t < 128) cnt[t] = 0;   // arrival counters for kmain
}

// Kernel B: main accumulation + FUSED last-arrival reduction. 1024 blocks =
// 128 b-tiles (8 b) x 8 i-chunks (32 i); grid co-resident at 4 blocks/CU.
// chunk = blk & 7 -> XCD-aligned; Cp slice written by same XCD (kperm).
// Prep: one (b,i) per thread. w-rows staged in LDS per 8-i batch.
// Epilogue: partials to part[chunk][b][o] (plain stores, unique writer);
// per-block threadfence + ONE arrival atomic per block (8 per counter,
// 1024 device-wide -- non-spinning, unlike R7's catastrophic poll loop);
// the 8th arriver invalidates L2 (fence) and reduces its 8x256 out-tile
// + bias. Saves the kreduce dispatch + inter-kernel drain/ramp gap.
__global__ __launch_bounds__(256, 4) void kmain(const float* __restrict__ x,
                                                const char* __restrict__ cpb,
                                                const float* __restrict__ wt,
                                                float4* __restrict__ part4,
                                                u32* __restrict__ cnt,
                                                const float4* __restrict__ bias4,
                                                float4* __restrict__ out4) {
    __shared__ float4 sf[256];           // [il][bl] : 32 i x 8 b   (4 KB)
    __shared__ float wbuf[8 * 256];      // 8 i-rows of w           (8 KB)
    __shared__ int lastArrival;
    int t = threadIdx.x;
    int blk = blockIdx.x;
    int chunk = blk & (NCH - 1);
    int bt = blk >> 3;                   // b-tile 0..127
    int b0 = bt << 3;                    // b-tile * 8
    int i0 = chunk << 5;                 // 32 i per chunk

    {                                    // prep: 1 (b,i) per thread
        int il = t & 31, bl = t >> 5;    // coalesced x reads along il
        float xv = x[(size_t)(b0 + bl) * Ii + i0 + il];
        float e2 = __expf(2.f * xv);
        float p = 1.f - 2.f / (e2 + 1.f);   // tanh
        float s = p / (1.f + __expf(-p));   // silu(p)
        float c = fminf(fmaxf(p, -1.f), 1.f);
        float scaled = (c + 1.f) * ((float)(Kk - 1) * 0.5f);
        int l = (int)floorf(scaled);
        l = min(max(l, 0), Kk - 1);
        int rr = min(l + 1, Kk - 1);
        float4 v;
        v.x = scaled - (float)l;             // frac
        v.y = s;                             // silu
        v.z = __int_as_float(l * (Oo * 2));  // byte ofs, left row in [k][o] slab
        v.w = __int_as_float(rr * (Oo * 2)); // byte ofs, right row
        sf[il * 8 + bl] = v;
    }

    int oq = t & 63;                     // o = oq*4 .. oq*4+3
    int bq = t >> 6;                     // 0..3 -> b = b0 + bq*2 + {0,1}

    float a00=0.f,a01=0.f,a02=0.f,a03=0.f;   // b = b0 + bq*2
    float a10=0.f,a11=0.f,a12=0.f,a13=0.f;   // b = b0 + bq*2 + 1
    const char* cbase = cpb + (size_t)i0 * (Kk * Oo * 2) + oq * 8;

#pragma unroll
    for (int jb = 0; jb < 4; ++jb) {
        __syncthreads();                 // prev batch's wbuf readers done
                                         // (jb==0: doubles as sf-prep barrier)
        {                                // stage 8 w-rows, once per block
            const float* wsrc = wt + (size_t)(i0 + jb * 8) * Oo;
#pragma unroll
            for (int p = 0; p < 8; ++p)
                wbuf[t + p * 256] = wsrc[t + p * 256];
        }
        __syncthreads();
#pragma unroll 4
        for (int m = 0; m < 8; ++m) {
            int il = jb * 8 + m;
            float4 v0 = sf[il * 8 + bq * 2];             // LDS broadcast
            float4 v1 = sf[il * 8 + bq * 2 + 1];
            float4 w = *(const float4*)&wbuf[m * 256 + oq * 4];  // b128, no conflicts
            const char* ci = cbase + (size_t)il * (Kk * Oo * 2);
            ushort4v cl0 = *(const ushort4v*)(ci + __float_as_int(v0.z));
            ushort4v cr0 = *(const ushort4v*)(ci + __float_as_int(v0.w));
            ushort4v cl1 = *(const ushort4v*)(ci + __float_as_int(v1.z));
            ushort4v cr1 = *(const ushort4v*)(ci + __float_as_int(v1.w));
            float f0 = v0.x, g0 = 1.f - v0.x, s0 = v0.y;
            float f1 = v1.x, g1 = 1.f - v1.x, s1 = v1.y;
            a00 = fmaf(s0, w.x, a00); a01 = fmaf(s0, w.y, a01);
            a02 = fmaf(s0, w.z, a02); a03 = fmaf(s0, w.w, a03);
            a10 = fmaf(s1, w.x, a10); a11 = fmaf(s1, w.y, a11);
            a12 = fmaf(s1, w.z, a12); a13 = fmaf(s1, w.w, a13);
            a00 = fmaf(g0, bf16u_to_f(cl0.x), a00); a00 = fmaf(f0, bf16u_to_f(cr0.x), a00);
            a01 = fmaf(g0, bf16u_to_f(cl0.y), a01); a01 = fmaf(f0, bf16u_to_f(cr0.y), a01);
            a02 = fmaf(g0, bf16u_to_f(cl0.z), a02); a02 = fmaf(f0, bf16u_to_f(cr0.z), a02);
            a03 = fmaf(g0, bf16u_to_f(cl0.w), a03); a03 = fmaf(f0, bf16u_to_f(cr0.w), a03);
            a10 = fmaf(g1, bf16u_to_f(cl1.x), a10); a10 = fmaf(f1, bf16u_to_f(cr1.x), a10);
            a11 = fmaf(g1, bf16u_to_f(cl1.y), a11); a11 = fmaf(f1, bf16u_to_f(cr1.y), a11);
            a12 = fmaf(g1, bf16u_to_f(cl1.z), a12); a12 = fmaf(f1, bf16u_to_f(cr1.z), a12);
            a13 = fmaf(g1, bf16u_to_f(cl1.w), a13); a13 = fmaf(f1, bf16u_to_f(cr1.w), a13);
        }
    }
    size_t cstride = (size_t)(Bb * Oo / 4);
    float4 r0; r0.x=a00; r0.y=a01; r0.z=a02; r0.w=a03;
    float4 r1; r1.x=a10; r1.y=a11; r1.z=a12; r1.w=a13;
    part4[chunk * cstride + (size_t)(b0 + bq * 2) * (Oo / 4) + oq] = r0;
    part4[chunk * cstride + (size_t)(b0 + bq * 2 + 1) * (Oo / 4) + oq] = r1;

    // ---- fused last-arrival reduction (canonical threadFenceReduction) ----
    __threadfence();                     // release this thread's part stores
    __syncthreads();
    if (t == 0) {
        u32 old = __hip_atomic_fetch_add(&cnt[bt], 1u, __ATOMIC_ACQ_REL,
                                         __HIP_MEMORY_SCOPE_AGENT);
        lastArrival = (old == (u32)(NCH - 1));
    }
    __syncthreads();
    if (lastArrival) {
        __threadfence();                 // acquire: invalidate stale L2 lines
        const float4* p = part4 + (size_t)b0 * (Oo / 4);
        float4* o4 = out4 + (size_t)b0 * (Oo / 4);
#pragma unroll
        for (int e = 0; e < 2; ++e) {
            int idx = e * 256 + t;       // 0..511 within the 8x256 tile
            float4 s = p[idx];
#pragma unroll
            for (int c = 1; c < NCH; ++c) {
                float4 v = p[idx + (size_t)c * cstride];
                s.x += v.x; s.y += v.y; s.z += v.z; s.w += v.w;
            }
            float4 bv = bias4[idx & 63];
            s.x += bv.x; s.y += bv.y; s.z += bv.z; s.w += bv.w;
            o4[idx] = s;
        }
    }
}

extern "C" void kernel_launch(void* const* d_in, const int* in_sizes, int n_in,
                              void* d_out, int out_size, void* d_ws, size_t ws_size,
                              hipStream_t stream) {
    const float* x     = (const float*)d_in[0];
    const float* wbase = (const float*)d_in[1];
    const float* coeff = (const float*)d_in[2];
    const float* scale = (const float*)d_in[3];
    const float* bias  = (const float*)d_in[4];
    float* out = (float*)d_out;

    char* ws = (char*)d_ws;
    u16*    cp    = (u16*)ws;                             // 16 MB @ 0
    float*  wt    = (float*)(ws + (16u << 20));           // 256 KB @ 16M
    float4* part4 = (float4*)(ws + (17u << 20));          // 8 MB @ 17M
    u32*    cnt   = (u32*)(ws + (25u << 20));             // 512 B @ 25M

    kperm<<<1024, 256, 0, stream>>>(coeff, scale, wbase, cp, wt, cnt);
    kmain<<<1024, 256, 0, stream>>>(x, (const char*)cp, wt, part4, cnt,
                                    (const float4*)bias, (float4*)out);
}

// Round 13
// 109.766 us; speedup vs baseline: 2.3840x; 2.3840x over previous
//
#include <hip/hip_runtime.h>

// Problem constants
constexpr int Bb = 1024;   // batch
constexpr int Ii = 256;    // in features
constexpr int Oo = 256;    // out features
constexpr int Kk = 128;    // knots
constexpr int NCH = 8;     // i-chunks (XCD-aligned)

typedef unsigned short u16;
typedef unsigned int u32;
typedef u16 ushort4v __attribute__((ext_vector_type(4)));

__device__ __forceinline__ float bf16u_to_f(u16 u) {
    union { u32 ui; float f; } c;
    c.ui = ((u32)u) << 16;
    return c.f;
}
__device__ __forceinline__ u16 f_to_bf16(float f) {  // round-to-nearest-even
    union { float f; u32 u; } c; c.f = f;
    u32 r = c.u + 0x7fffu + ((c.u >> 16) & 1u);
    return (u16)(r >> 16);
}

// Kernel A: permute+scale Cs[o][i][k] -> Cp[i][k][o] bf16 via LDS transpose.
// 1024 blocks, XCD-ALIGNED numbering: chunk = blk & 7 (same mapping as
// kmain's readers) -> chunk c's 2 MB Cp slice is written by XCD c and stays
// valid-clean in XCD c's L2 for kmain's local-L2 gather hits.
// Tile = 128 o x 64 k; reads coalesced along k, writes coalesced along o;
// LDS pitch 66 u16 -> conflict-free. Tail on blocks < 256: Wt[i][o]=W[o][i].
// NOTE (R7/R12 lessons): NO device-scope fences/atomics/spins inside
// co-resident kernels on MI355X -- __threadfence storms flush the XCD L2s
// and serialize everything (R12: kmain 25 -> 205 us). Dependencies stay at
// dispatch granularity.
__global__ __launch_bounds__(256) void kperm(const float* __restrict__ cs,
                                             const float* __restrict__ scale,
                                             const float* __restrict__ wbase,
                                             u16* __restrict__ cp,
                                             float* __restrict__ wt) {
    __shared__ u16 T[128 * 66];       // [o_local][k_local], pitch 66
    int blk = blockIdx.x;
    int chunk = blk & 7;
    int sub = blk >> 3;               // 0..127
    int i  = chunk * 32 + (sub & 31); // i within this XCD's chunk
    int oh = (sub >> 5) & 1, kh = (sub >> 6) & 1;
    int o0 = oh << 7, kb = kh << 6;
    int t = threadIdx.x;

    // Phase 1: load Cs rows (float4 along k), scale, bf16 -> LDS
    {
        int c4 = t & 15;              // float4 index within the 64-k half
        int rb = t >> 4;              // 0..15
        const float4* cs4 = (const float4*)cs;
#pragma unroll
        for (int p = 0; p < 8; ++p) {
            int r = p * 16 + rb;      // o_local 0..127
            int o = o0 + r;
            float sc = scale[o * Ii + i];
            float4 val = cs4[(size_t)(o * Ii + i) * (Kk / 4) + kh * 16 + c4];
            int kl = c4 * 4;
            T[r * 66 + kl + 0] = f_to_bf16(val.x * sc);
            T[r * 66 + kl + 1] = f_to_bf16(val.y * sc);
            T[r * 66 + kl + 2] = f_to_bf16(val.z * sc);
            T[r * 66 + kl + 3] = f_to_bf16(val.w * sc);
        }
    }
    __syncthreads();
    // Phase 2: write Cp[i][kb+kl][o0..o0+128], lanes <-> o (u32 = 2 o)
    {
        int og = t & 63;              // o-pair index (o = og*2, og*2+1)
        int kg = t >> 6;              // 0..3, 16 k-rows each
#pragma unroll
        for (int m = 0; m < 16; ++m) {
            int kl = kg * 16 + m;
            u32 lo = T[(og * 2) * 66 + kl];
            u32 hi = T[(og * 2 + 1) * 66 + kl];
            *(u32*)&cp[((size_t)i * Kk + kb + kl) * Oo + o0 + og * 2] = lo | (hi << 16);
        }
    }
    // Tail: Wt[i][o] = W[o][i] (65536 elems across blocks 0..255)
    if (blk < 256) {
        int gid = blk * 256 + t;
        wt[gid] = wbase[(gid & 255) * Ii + (gid >> 8)];
    }
}

// Kernel B: main accumulation, 8-b tiles. 1024 blocks = 128 b-tiles (8 b)
// x 8 i-chunks (32 i); grid exactly co-resident at 4 blocks/CU.
// chunk = blk & 7 -> XCD-aligned; Cp slice written by same XCD (kperm).
// Prep: exactly one (b,i) value per thread. w-rows staged in LDS per
// 8-i batch (once per block, not per wave).
// Partials to part[chunk][b][o] (plain stores, unique writer); kreduce sums.
__global__ __launch_bounds__(256, 4) void kmain(const float* __restrict__ x,
                                                const char* __restrict__ cpb,
                                                const float* __restrict__ wt,
                                                float4* __restrict__ part4) {
    __shared__ float4 sf[256];           // [il][bl] : 32 i x 8 b   (4 KB)
    __shared__ float wbuf[8 * 256];      // 8 i-rows of w           (8 KB)
    int t = threadIdx.x;
    int blk = blockIdx.x;
    int chunk = blk & (NCH - 1);
    int b0 = (blk >> 3) << 3;            // b-tile * 8
    int i0 = chunk << 5;                 // 32 i per chunk

    {                                    // prep: 1 (b,i) per thread
        int il = t & 31, bl = t >> 5;    // coalesced x reads along il
        float xv = x[(size_t)(b0 + bl) * Ii + i0 + il];
        float e2 = __expf(2.f * xv);
        float p = 1.f - 2.f / (e2 + 1.f);   // tanh
        float s = p / (1.f + __expf(-p));   // silu(p)
        float c = fminf(fmaxf(p, -1.f), 1.f);
        float scaled = (c + 1.f) * ((float)(Kk - 1) * 0.5f);
        int l = (int)floorf(scaled);
        l = min(max(l, 0), Kk - 1);
        int rr = min(l + 1, Kk - 1);
        float4 v;
        v.x = scaled - (float)l;             // frac
        v.y = s;                             // silu
        v.z = __int_as_float(l * (Oo * 2));  // byte ofs, left row in [k][o] slab
        v.w = __int_as_float(rr * (Oo * 2)); // byte ofs, right row
        sf[il * 8 + bl] = v;
    }

    int oq = t & 63;                     // o = oq*4 .. oq*4+3
    int bq = t >> 6;                     // 0..3 -> b = b0 + bq*2 + {0,1}

    float a00=0.f,a01=0.f,a02=0.f,a03=0.f;   // b = b0 + bq*2
    float a10=0.f,a11=0.f,a12=0.f,a13=0.f;   // b = b0 + bq*2 + 1
    const char* cbase = cpb + (size_t)i0 * (Kk * Oo * 2) + oq * 8;

#pragma unroll
    for (int jb = 0; jb < 4; ++jb) {
        __syncthreads();                 // prev batch's wbuf readers done
                                         // (jb==0: doubles as sf-prep barrier)
        {                                // stage 8 w-rows, once per block
            const float* wsrc = wt + (size_t)(i0 + jb * 8) * Oo;
#pragma unroll
            for (int p = 0; p < 8; ++p)
                wbuf[t + p * 256] = wsrc[t + p * 256];
        }
        __syncthreads();
#pragma unroll 4
        for (int m = 0; m < 8; ++m) {
            int il = jb * 8 + m;
            float4 v0 = sf[il * 8 + bq * 2];             // LDS broadcast
            float4 v1 = sf[il * 8 + bq * 2 + 1];
            float4 w = *(const float4*)&wbuf[m * 256 + oq * 4];  // b128, no conflicts
            const char* ci = cbase + (size_t)il * (Kk * Oo * 2);
            ushort4v cl0 = *(const ushort4v*)(ci + __float_as_int(v0.z));
            ushort4v cr0 = *(const ushort4v*)(ci + __float_as_int(v0.w));
            ushort4v cl1 = *(const ushort4v*)(ci + __float_as_int(v1.z));
            ushort4v cr1 = *(const ushort4v*)(ci + __float_as_int(v1.w));
            float f0 = v0.x, g0 = 1.f - v0.x, s0 = v0.y;
            float f1 = v1.x, g1 = 1.f - v1.x, s1 = v1.y;
            a00 = fmaf(s0, w.x, a00); a01 = fmaf(s0, w.y, a01);
            a02 = fmaf(s0, w.z, a02); a03 = fmaf(s0, w.w, a03);
            a10 = fmaf(s1, w.x, a10); a11 = fmaf(s1, w.y, a11);
            a12 = fmaf(s1, w.z, a12); a13 = fmaf(s1, w.w, a13);
            a00 = fmaf(g0, bf16u_to_f(cl0.x), a00); a00 = fmaf(f0, bf16u_to_f(cr0.x), a00);
            a01 = fmaf(g0, bf16u_to_f(cl0.y), a01); a01 = fmaf(f0, bf16u_to_f(cr0.y), a01);
            a02 = fmaf(g0, bf16u_to_f(cl0.z), a02); a02 = fmaf(f0, bf16u_to_f(cr0.z), a02);
            a03 = fmaf(g0, bf16u_to_f(cl0.w), a03); a03 = fmaf(f0, bf16u_to_f(cr0.w), a03);
            a10 = fmaf(g1, bf16u_to_f(cl1.x), a10); a10 = fmaf(f1, bf16u_to_f(cr1.x), a10);
            a11 = fmaf(g1, bf16u_to_f(cl1.y), a11); a11 = fmaf(f1, bf16u_to_f(cr1.y), a11);
            a12 = fmaf(g1, bf16u_to_f(cl1.z), a12); a12 = fmaf(f1, bf16u_to_f(cr1.z), a12);
            a13 = fmaf(g1, bf16u_to_f(cl1.w), a13); a13 = fmaf(f1, bf16u_to_f(cr1.w), a13);
        }
    }
    size_t cstride = (size_t)(Bb * Oo / 4);
    float4 r0; r0.x=a00; r0.y=a01; r0.z=a02; r0.w=a03;
    float4 r1; r1.x=a10; r1.y=a11; r1.z=a12; r1.w=a13;
    part4[chunk * cstride + (size_t)(b0 + bq * 2) * (Oo / 4) + oq] = r0;
    part4[chunk * cstride + (size_t)(b0 + bq * 2 + 1) * (Oo / 4) + oq] = r1;
}

// Kernel C: out[b][o] = bias[o] + sum_c partial[c][b][o]. 256 blocks.
__global__ __launch_bounds__(256) void kreduce(const float4* __restrict__ part4,
                                               const float4* __restrict__ bias4,
                                               float4* __restrict__ out4) {
    int gid = blockIdx.x * 256 + threadIdx.x;     // = b*64 + o4
    const float4* p = part4 + gid;
    float4 s = p[0];
#pragma unroll
    for (int c = 1; c < NCH; ++c) {
        float4 v = p[(size_t)c * (Bb * Oo / 4)];
        s.x += v.x; s.y += v.y; s.z += v.z; s.w += v.w;
    }
    float4 bv = bias4[gid & 63];
    s.x += bv.x; s.y += bv.y; s.z += bv.z; s.w += bv.w;
    out4[gid] = s;
}

extern "C" void kernel_launch(void* const* d_in, const int* in_sizes, int n_in,
                              void* d_out, int out_size, void* d_ws, size_t ws_size,
                              hipStream_t stream) {
    const float* x     = (const float*)d_in[0];
    const float* wbase = (const float*)d_in[1];
    const float* coeff = (const float*)d_in[2];
    const float* scale = (const float*)d_in[3];
    const float* bias  = (const float*)d_in[4];
    float* out = (float*)d_out;

    char* ws = (char*)d_ws;
    u16*    cp    = (u16*)ws;                             // 16 MB @ 0
    float*  wt    = (float*)(ws + (16u << 20));           // 256 KB @ 16M
    float4* part4 = (float4*)(ws + (17u << 20));          // 8 MB @ 17M

    kperm<<<1024, 256, 0, stream>>>(coeff, scale, wbase, cp, wt);
    kmain<<<1024, 256, 0, stream>>>(x, (const char*)cp, wt, part4);
    kreduce<<<(Bb * Oo / 4) / 256, 256, 0, stream>>>(part4, (const float4*)bias, (float4*)out);
}